// Round 9
// baseline (4767.690 us; speedup 1.0000x reference)
//
#include <hip/hip_runtime.h>
#include <hip/hip_bf16.h>
#include <stdint.h>

#define NB 128
#define NT 512
#define NI 256
#define NH 256
#define NG 768          // 3*NH

typedef unsigned int u32;
typedef unsigned short u16;
typedef __attribute__((ext_vector_type(8))) short short8;
typedef __attribute__((ext_vector_type(4))) float f32x4;

__device__ __forceinline__ float lo_bf(u32 u){ return __uint_as_float(u << 16); }
__device__ __forceinline__ float hi_bf(u32 u){ return __uint_as_float(u & 0xffff0000u); }
__device__ __forceinline__ u16 f2bf(float f){
  u32 u = __float_as_uint(f);
  u += 0x7fffu + ((u >> 16) & 1u);   // RNE
  return (u16)(u >> 16);
}
__device__ __forceinline__ u32 pack2(float a, float b){
  return (u32)f2bf(a) | ((u32)f2bf(b) << 16);
}
__device__ __forceinline__ u32 pack_rne(float a, float b){
  u32 ua = __float_as_uint(a), ub = __float_as_uint(b);
  ua += 0x7fffu + ((ua >> 16) & 1u);
  ub += 0x7fffu + ((ub >> 16) & 1u);
  return (ua >> 16) | (ub & 0xffff0000u);
}
__device__ __forceinline__ float sigf(float v){
  return __builtin_amdgcn_rcpf(1.f + __expf(-v));
}
__device__ __forceinline__ float tanhf_(float u){
  float e = __expf(2.f*u);
  return 1.f - 2.f*__builtin_amdgcn_rcpf(e + 1.f);
}
__device__ __forceinline__ void gload_lds16(const void* g, void* l){
  __builtin_amdgcn_global_load_lds((const __attribute__((address_space(1))) void*)g,
                                   (__attribute__((address_space(3))) void*)l, 16, 0, 0);
}

// ---------------------------------------------------------------------------
// fp32 -> bf16 conversions + combined bias vectors (both layers)
// ---------------------------------------------------------------------------
__global__ void convert_kernel(const float* __restrict__ x,
    const float* __restrict__ Wih0, const float* __restrict__ Wih1,
    const float* __restrict__ bih0, const float* __restrict__ bhh0,
    const float* __restrict__ bih1, const float* __restrict__ bhh1,
    u16* __restrict__ xbf, u16* __restrict__ w0bf, u16* __restrict__ w1bf,
    float* __restrict__ bias0, float* __restrict__ bias1)
{
  const int NX4 = NB*NT*NI/4, NW4 = NG*NH/4;
  int gid = blockIdx.x*blockDim.x + threadIdx.x;
  for (int i = gid; i < NX4 + 2*NW4; i += gridDim.x*blockDim.x) {
    const float* s; u16* d; int o;
    if (i < NX4)          { s = x;    d = xbf;  o = i; }
    else if (i < NX4+NW4) { s = Wih0; d = w0bf; o = i - NX4; }
    else                  { s = Wih1; d = w1bf; o = i - NX4 - NW4; }
    float4 v = *(const float4*)(s + (size_t)o*4);
    uint2 pk; pk.x = pack2(v.x, v.y); pk.y = pack2(v.z, v.w);
    *(uint2*)&d[(size_t)o*4] = pk;
  }
  if (gid < NG)            bias0[gid] = bih0[gid] + (gid < 2*NH ? bhh0[gid] : 0.f);
  else if (gid < 2*NG)   { int g = gid - NG; bias1[g] = bih1[g] + (g < 2*NH ? bhh1[g] : 0.f); }
}

// ---------------------------------------------------------------------------
// xproj[m][g] = sum_k A[m][k] * W[g][k] + bias[g]    (A:[M][256], W:[768][256])
// ---------------------------------------------------------------------------
__global__ __launch_bounds__(256, 2) void gemm_proj(const u16* __restrict__ A,
    const u16* __restrict__ W, const float* __restrict__ bias, u16* __restrict__ out)
{
  const int mt = blockIdx.x / 24, nt = blockIdx.x % 24;
  __shared__ __align__(16) u16 As[64*256];
  __shared__ __align__(16) u16 Bs[32*256];
  const int tid = threadIdx.x;
  const u16* Ag = A + (size_t)mt*64*256;
  const u16* Wg = W + (size_t)nt*32*256;
  #pragma unroll
  for (int i = 0; i < 8; ++i) {
    int ca = tid + 256*i, row = ca >> 5, sl = ca & 31;
    gload_lds16(Ag + row*256 + ((sl ^ (row&7))<<3), &As[ca<<3]);
  }
  #pragma unroll
  for (int i = 0; i < 4; ++i) {
    int cb = tid + 256*i, row = cb >> 5, sl = cb & 31;
    gload_lds16(Wg + row*256 + ((sl ^ (row&7))<<3), &Bs[cb<<3]);
  }
  __syncthreads();
  const int w = tid >> 6, l = tid & 63, c = l & 15, q = l >> 4;
  f32x4 acc0 = {0.f,0.f,0.f,0.f}, acc1 = acc0;
  const int arow = w*16 + c;
  #pragma unroll
  for (int kb = 0; kb < 8; ++kb) {
    int ks = kb*4 + q;
    short8 af  = *(const short8*)&As[arow*256 + ((ks ^ (arow&7))<<3)];
    short8 bf0 = *(const short8*)&Bs[c*256        + ((ks ^ (c&7))<<3)];
    short8 bf1 = *(const short8*)&Bs[(16+c)*256   + ((ks ^ ((16+c)&7))<<3)];
    acc0 = __builtin_amdgcn_mfma_f32_16x16x32_bf16(af, bf0, acc0, 0,0,0);
    acc1 = __builtin_amdgcn_mfma_f32_16x16x32_bf16(af, bf1, acc1, 0,0,0);
  }
  #pragma unroll
  for (int nf = 0; nf < 2; ++nf) {
    int g = nt*32 + nf*16 + c;
    float bs = bias[g];
    f32x4 av = nf ? acc1 : acc0;
    #pragma unroll
    for (int r = 0; r < 4; ++r) {
      int m = mt*64 + w*16 + q*4 + r;
      out[(size_t)m*NG + g] = f2bf(av[r] + bs);
    }
  }
}

// ---------------------------------------------------------------------------
// GRU recurrence v4: 16 wgs x 512 thr, 8 batches per wg as TWO interleaved
// 4-batch groups (A,B) sharing resident weights. One barrier per superstep:
// readA+readB -> MFMA-A -> MFMA-B -> gates-A -> gates-B -> prefetch -> barrier.
// Lane (c,q): batch=c&3, jh=c>>3, rs=(c>>2)&1 -> 2 h-values per group.
// ---------------------------------------------------------------------------
__global__ __launch_bounds__(512, 1) void recur_kernel(
    const u16* __restrict__ xproj,   // [NB*NT][768] bf16 (biases folded; r,z incl bhh)
    const float* __restrict__ Whh,   // [768][256] fp32
    const float* __restrict__ bhh,   // [768] fp32 (n part used)
    u16* __restrict__ outp,          // write_all: [NB][NT][256] ; else hT [NB][256]
    int write_all)
{
  const int b0 = blockIdx.x * 8;
  const int tid = threadIdx.x;
  const int w = tid >> 6, l = tid & 63, c = l & 15, q = l >> 4;
  const int jh = c >> 3;                 // tile half
  const int rs = (c >> 2) & 1;           // r-pair within tile
  const bool lo8 = (jh == 0);
  const bool rlo = (rs == 0);
  const int bbA = b0 + (c & 3);          // group A batch
  const int bbB = b0 + 4 + (c & 3);      // group B batch
  const int j0 = 32*w + jh*16 + q*4 + 2*rs;   // lane's first output j

  __shared__ __align__(16) u16 hfrag[2][2][8][512];   // [grp][buf][kb][...] 32 KB
  for (int i = tid; i < 8192; i += 512) ((u32*)hfrag)[i] = 0u;

  // ---- resident weight fragments wf[gate][jj][kb] (48 frags, shared) ----
  short8 wf[3][2][8];
  #pragma unroll
  for (int g = 0; g < 3; ++g)
    #pragma unroll
    for (int jj = 0; jj < 2; ++jj) {
      const float* src = Whh + ((size_t)(g*NH + 32*w + jj*16 + c))*NI + q*8;
      #pragma unroll
      for (int kb = 0; kb < 8; ++kb) {
        float4 f0 = *(const float4*)(src + kb*32);
        float4 f1 = *(const float4*)(src + kb*32 + 4);
        short8 s;
        s[0]=(short)f2bf(f0.x); s[1]=(short)f2bf(f0.y);
        s[2]=(short)f2bf(f0.z); s[3]=(short)f2bf(f0.w);
        s[4]=(short)f2bf(f1.x); s[5]=(short)f2bf(f1.y);
        s[6]=(short)f2bf(f1.z); s[7]=(short)f2bf(f1.w);
        wf[g][jj][kb] = s;
      }
    }

  // n-gate hidden-bias accumulator init (rows q*4..+3 of each tile half)
  float4 bt0 = *(const float4*)&bhh[2*NH + 32*w + q*4];
  float4 bt1 = *(const float4*)&bhh[2*NH + 32*w + q*4 + 16];
  f32x4 bhn0; bhn0[0]=bt0.x; bhn0[1]=bt0.y; bhn0[2]=bt0.z; bhn0[3]=bt0.w;
  f32x4 bhn1; bhn1[0]=bt1.x; bhn1[1]=bt1.y; bhn1[2]=bt1.z; bhn1[3]=bt1.w;

  // xproj pointers (per-lane, per-group)
  const u16* xptrA = xproj + (size_t)bbA*NT*NG + j0;
  const u16* xptrB = xproj + (size_t)bbB*NT*NG + j0;
  u32 xAr = *(const u32*)(xptrA);
  u32 xAz = *(const u32*)(xptrA + NH);
  u32 xAn = *(const u32*)(xptrA + 2*NH);
  u32 xBr = *(const u32*)(xptrB);
  u32 xBz = *(const u32*)(xptrB + NH);
  u32 xBn = *(const u32*)(xptrB + 2*NH);
  u32 pAr = *(const u32*)(xptrA + NG);
  u32 pAz = *(const u32*)(xptrA + NG + NH);
  u32 pAn = *(const u32*)(xptrA + NG + 2*NH);
  u32 pBr = *(const u32*)(xptrB + NG);
  u32 pBz = *(const u32*)(xptrB + NG + NH);
  u32 pBn = *(const u32*)(xptrB + NG + 2*NH);
  u32 hpkA = 0u, hpkB = 0u;

  // LDS write base (verified R8 mapping): 4 duplicated column copies
  const int lpb  = (c & 3) + 16*(2*jh + (q >> 1));
  const int elds = 4*(q & 1) + 2*rs;
  const int woff = lpb*8 + elds;         // u16 units within hfrag[g][.][w]

  __syncthreads();

  #pragma unroll 1
  for (int t = 0; t < NT; ++t) {
    const int cur = t & 1, nxt = cur ^ 1;

    // ---- B-fragment reads for BOTH groups (16 x ds_read_b128) ----
    short8 bfA[8], bfB[8];
    #pragma unroll
    for (int kb = 0; kb < 8; ++kb) bfA[kb] = *(const short8*)&hfrag[0][cur][kb][l*8];
    #pragma unroll
    for (int kb = 0; kb < 8; ++kb) bfB[kb] = *(const short8*)&hfrag[1][cur][kb][l*8];

    // ---- MFMA group A (6 chains x 8) ----
    f32x4 z4 = {0.f,0.f,0.f,0.f};
    f32x4 aAr0 = z4, aAz0 = z4, aAr1 = z4, aAz1 = z4;
    f32x4 aAn0 = bhn0, aAn1 = bhn1;
    #pragma unroll
    for (int kb = 0; kb < 8; ++kb) {
      short8 bv = bfA[kb];
      aAr0 = __builtin_amdgcn_mfma_f32_16x16x32_bf16(wf[0][0][kb], bv, aAr0, 0,0,0);
      aAz0 = __builtin_amdgcn_mfma_f32_16x16x32_bf16(wf[1][0][kb], bv, aAz0, 0,0,0);
      aAn0 = __builtin_amdgcn_mfma_f32_16x16x32_bf16(wf[2][0][kb], bv, aAn0, 0,0,0);
      aAr1 = __builtin_amdgcn_mfma_f32_16x16x32_bf16(wf[0][1][kb], bv, aAr1, 0,0,0);
      aAz1 = __builtin_amdgcn_mfma_f32_16x16x32_bf16(wf[1][1][kb], bv, aAz1, 0,0,0);
      aAn1 = __builtin_amdgcn_mfma_f32_16x16x32_bf16(wf[2][1][kb], bv, aAn1, 0,0,0);
    }
    // ---- MFMA group B (independent; hides A's completion latency) ----
    f32x4 aBr0 = z4, aBz0 = z4, aBr1 = z4, aBz1 = z4;
    f32x4 aBn0 = bhn0, aBn1 = bhn1;
    #pragma unroll
    for (int kb = 0; kb < 8; ++kb) {
      short8 bv = bfB[kb];
      aBr0 = __builtin_amdgcn_mfma_f32_16x16x32_bf16(wf[0][0][kb], bv, aBr0, 0,0,0);
      aBz0 = __builtin_amdgcn_mfma_f32_16x16x32_bf16(wf[1][0][kb], bv, aBz0, 0,0,0);
      aBn0 = __builtin_amdgcn_mfma_f32_16x16x32_bf16(wf[2][0][kb], bv, aBn0, 0,0,0);
      aBr1 = __builtin_amdgcn_mfma_f32_16x16x32_bf16(wf[0][1][kb], bv, aBr1, 0,0,0);
      aBz1 = __builtin_amdgcn_mfma_f32_16x16x32_bf16(wf[1][1][kb], bv, aBz1, 0,0,0);
      aBn1 = __builtin_amdgcn_mfma_f32_16x16x32_bf16(wf[2][1][kb], bv, aBn1, 0,0,0);
    }

    // ---- gates group A: 2 h-values ----
    {
      float hv[2];
      #pragma unroll
      for (int e = 0; e < 2; ++e) {
        float a0 = rlo ? aAr0[e] : aAr0[2+e];
        float a1 = rlo ? aAr1[e] : aAr1[2+e];
        float arv = lo8 ? a0 : a1;
        float z0 = rlo ? aAz0[e] : aAz0[2+e];
        float z1 = rlo ? aAz1[e] : aAz1[2+e];
        float azv = lo8 ? z0 : z1;
        float n0 = rlo ? aAn0[e] : aAn0[2+e];
        float n1 = rlo ? aAn1[e] : aAn1[2+e];
        float anv = lo8 ? n0 : n1;
        float xr = e ? hi_bf(xAr) : lo_bf(xAr);
        float xz = e ? hi_bf(xAz) : lo_bf(xAz);
        float xn = e ? hi_bf(xAn) : lo_bf(xAn);
        float hp = e ? hi_bf(hpkA) : lo_bf(hpkA);
        float rr = sigf(xr + arv);
        float zz = sigf(xz + azv);
        float nn = tanhf_(__builtin_fmaf(rr, anv, xn));
        hv[e] = __builtin_fmaf(zz, hp - nn, nn);
      }
      hpkA = pack_rne(hv[0], hv[1]);
      u16* hd = &hfrag[0][nxt][w][woff];
      *(u32*)(hd)       = hpkA;
      *(u32*)(hd + 32)  = hpkA;
      *(u32*)(hd + 64)  = hpkA;
      *(u32*)(hd + 96)  = hpkA;
      if (write_all)
        *(u32*)&outp[((size_t)bbA*NT + t)*NH + j0] = hpkA;
      else if (t == NT-1)
        *(u32*)&outp[(size_t)bbA*NH + j0] = hpkA;
    }
    // ---- gates group B ----
    {
      float hv[2];
      #pragma unroll
      for (int e = 0; e < 2; ++e) {
        float a0 = rlo ? aBr0[e] : aBr0[2+e];
        float a1 = rlo ? aBr1[e] : aBr1[2+e];
        float arv = lo8 ? a0 : a1;
        float z0 = rlo ? aBz0[e] : aBz0[2+e];
        float z1 = rlo ? aBz1[e] : aBz1[2+e];
        float azv = lo8 ? z0 : z1;
        float n0 = rlo ? aBn0[e] : aBn0[2+e];
        float n1 = rlo ? aBn1[e] : aBn1[2+e];
        float anv = lo8 ? n0 : n1;
        float xr = e ? hi_bf(xBr) : lo_bf(xBr);
        float xz = e ? hi_bf(xBz) : lo_bf(xBz);
        float xn = e ? hi_bf(xBn) : lo_bf(xBn);
        float hp = e ? hi_bf(hpkB) : lo_bf(hpkB);
        float rr = sigf(xr + arv);
        float zz = sigf(xz + azv);
        float nn = tanhf_(__builtin_fmaf(rr, anv, xn));
        hv[e] = __builtin_fmaf(zz, hp - nn, nn);
      }
      hpkB = pack_rne(hv[0], hv[1]);
      u16* hd = &hfrag[1][nxt][w][woff];
      *(u32*)(hd)       = hpkB;
      *(u32*)(hd + 32)  = hpkB;
      *(u32*)(hd + 64)  = hpkB;
      *(u32*)(hd + 96)  = hpkB;
      if (write_all)
        *(u32*)&outp[((size_t)bbB*NT + t)*NH + j0] = hpkB;
      else if (t == NT-1)
        *(u32*)&outp[(size_t)bbB*NH + j0] = hpkB;
    }

    // ---- depth-2 xproj prefetch rotate (both groups) ----
    xAr = pAr; xAz = pAz; xAn = pAn;
    xBr = pBr; xBz = pBz; xBn = pBn;
    if (t + 2 < NT) {
      const u16* xa = xptrA + (size_t)(t+2)*NG;
      const u16* xb = xptrB + (size_t)(t+2)*NG;
      pAr = *(const u32*)(xa);
      pAz = *(const u32*)(xa + NH);
      pAn = *(const u32*)(xa + 2*NH);
      pBr = *(const u32*)(xb);
      pBz = *(const u32*)(xb + NH);
      pBn = *(const u32*)(xb + 2*NH);
    }

    // ---- one raw barrier per superstep (LDS drain only) ----
    asm volatile("s_waitcnt lgkmcnt(0)" ::: "memory");
    __builtin_amdgcn_s_barrier();
    __builtin_amdgcn_sched_barrier(0);
  }
}

// ---------------------------------------------------------------------------
__global__ __launch_bounds__(256) void fc_kernel(const u16* __restrict__ hT,
    const float* __restrict__ Wfc, const float* __restrict__ bfc, float* __restrict__ out)
{
  __shared__ float wv[NH];
  int tid = threadIdx.x;
  if (tid < NH) wv[tid] = Wfc[tid];
  __syncthreads();
  if (tid < NB) {
    float acc = bfc[0];
    for (int j = 0; j < NH; ++j) acc += lo_bf((u32)hT[tid*NH + j]) * wv[j];
    out[tid] = sigf(acc);
  }
}

// ---------------------------------------------------------------------------
extern "C" void kernel_launch(void* const* d_in, const int* in_sizes, int n_in,
                              void* d_out, int out_size, void* d_ws, size_t ws_size,
                              hipStream_t stream) {
  const float* x    = (const float*)d_in[0];
  const float* Wih0 = (const float*)d_in[1];
  const float* Whh0 = (const float*)d_in[2];
  const float* bih0 = (const float*)d_in[3];
  const float* bhh0 = (const float*)d_in[4];
  const float* Wih1 = (const float*)d_in[5];
  const float* Whh1 = (const float*)d_in[6];
  const float* bih1 = (const float*)d_in[7];
  const float* bhh1 = (const float*)d_in[8];
  const float* Wfc  = (const float*)d_in[9];
  const float* bfc  = (const float*)d_in[10];

  char* ws = (char*)d_ws;
  u16*   xproj = (u16*)ws;                                   // 100,663,296 B
  u16*   xbf   = (u16*)(ws + 100663296);                     // 33,554,432 B
  u16*   out0  = xbf;                                        // aliases xbf (dead after GEMM0)
  u16*   w0bf  = (u16*)(ws + 134217728);
  u16*   w1bf  = (u16*)(ws + 134610944);
  float* bias0 = (float*)(ws + 135004160);
  float* bias1 = (float*)(ws + 135007232);
  u16*   hT    = (u16*)(ws + 135010304);

  convert_kernel<<<dim3(2048), dim3(256), 0, stream>>>(
      x, Wih0, Wih1, bih0, bhh0, bih1, bhh1, xbf, w0bf, w1bf, bias0, bias1);
  gemm_proj<<<dim3(1024*24), dim3(256), 0, stream>>>(xbf, w0bf, bias0, xproj);
  recur_kernel<<<dim3(16), dim3(512), 0, stream>>>(xproj, Whh0, bhh0, out0, 1);
  gemm_proj<<<dim3(1024*24), dim3(256), 0, stream>>>(out0, w1bf, bias1, xproj);
  recur_kernel<<<dim3(16), dim3(512), 0, stream>>>(xproj, Whh1, bhh1, hT, 0);
  fc_kernel<<<dim3(1), dim3(256), 0, stream>>>(hT, Wfc, bfc, (float*)d_out);
}

// Round 10
// 1421.341 us; speedup vs baseline: 3.3544x; 3.3544x over previous
//
#include <hip/hip_runtime.h>
#include <hip/hip_bf16.h>
#include <stdint.h>

#define NB 128
#define NT 512
#define NI 256
#define NH 256
#define NG 768          // 3*NH

typedef unsigned int u32;
typedef unsigned short u16;
typedef __attribute__((ext_vector_type(8))) short short8;
typedef __attribute__((ext_vector_type(4))) float f32x4;

__device__ __forceinline__ float lo_bf(u32 u){ return __uint_as_float(u << 16); }
__device__ __forceinline__ float hi_bf(u32 u){ return __uint_as_float(u & 0xffff0000u); }
__device__ __forceinline__ u16 f2bf(float f){
  u32 u = __float_as_uint(f);
  u += 0x7fffu + ((u >> 16) & 1u);   // RNE
  return (u16)(u >> 16);
}
__device__ __forceinline__ u32 pack2(float a, float b){
  return (u32)f2bf(a) | ((u32)f2bf(b) << 16);
}
__device__ __forceinline__ u32 pack_rne(float a, float b){
  u32 ua = __float_as_uint(a), ub = __float_as_uint(b);
  ua += 0x7fffu + ((ua >> 16) & 1u);
  ub += 0x7fffu + ((ub >> 16) & 1u);
  return (ua >> 16) | (ub & 0xffff0000u);
}
__device__ __forceinline__ float sigf(float v){
  return __builtin_amdgcn_rcpf(1.f + __expf(-v));
}
__device__ __forceinline__ float tanhf_(float u){
  float e = __expf(2.f*u);
  return 1.f - 2.f*__builtin_amdgcn_rcpf(e + 1.f);
}
__device__ __forceinline__ void gload_lds16(const void* g, void* l){
  __builtin_amdgcn_global_load_lds((const __attribute__((address_space(1))) void*)g,
                                   (__attribute__((address_space(3))) void*)l, 16, 0, 0);
}

// ---------------------------------------------------------------------------
// weights fp32 -> bf16 + combined bias vectors (x stays fp32; gemm0 converts)
// ---------------------------------------------------------------------------
__global__ void convert_kernel(
    const float* __restrict__ Wih0, const float* __restrict__ Wih1,
    const float* __restrict__ bih0, const float* __restrict__ bhh0,
    const float* __restrict__ bih1, const float* __restrict__ bhh1,
    u16* __restrict__ w0bf, u16* __restrict__ w1bf,
    float* __restrict__ bias0, float* __restrict__ bias1)
{
  const int NW4 = NG*NH/4;
  int gid = blockIdx.x*blockDim.x + threadIdx.x;
  for (int i = gid; i < 2*NW4; i += gridDim.x*blockDim.x) {
    const float* s; u16* d; int o;
    if (i < NW4) { s = Wih0; d = w0bf; o = i; }
    else         { s = Wih1; d = w1bf; o = i - NW4; }
    float4 v = *(const float4*)(s + (size_t)o*4);
    uint2 pk; pk.x = pack2(v.x, v.y); pk.y = pack2(v.z, v.w);
    *(uint2*)&d[(size_t)o*4] = pk;
  }
  if (gid < NG)            bias0[gid] = bih0[gid] + (gid < 2*NH ? bhh0[gid] : 0.f);
  else if (gid < 2*NG)   { int g = gid - NG; bias1[g] = bih1[g] + (g < 2*NH ? bhh1[g] : 0.f); }
}

// ---------------------------------------------------------------------------
// xproj[m][g] = sum_k A[m][k] * W[g][k] + bias[g]    (A:[M][256], W:[768][256])
// A_F32: A is fp32 (reg-staged + converted); else bf16 via global_load_lds.
// ---------------------------------------------------------------------------
template <bool A_F32>
__global__ __launch_bounds__(256, 2) void gemm_proj(const void* __restrict__ Ap,
    const u16* __restrict__ W, const float* __restrict__ bias, u16* __restrict__ out)
{
  const int mt = blockIdx.x / 24, nt = blockIdx.x % 24;
  __shared__ __align__(16) u16 As[64*256];   // 32 KB
  __shared__ __align__(16) u16 Bs[32*256];   // 16 KB
  const int tid = threadIdx.x;
  #pragma unroll
  for (int i = 0; i < 8; ++i) {              // A: 2048 16B-bf16 chunks
    int ca = tid + 256*i, row = ca >> 5, sl = ca & 31;
    if (A_F32) {
      const float* Ag = (const float*)Ap + (size_t)mt*64*256;
      const float* src = Ag + row*256 + sl*8;
      float4 f0 = *(const float4*)(src);
      float4 f1 = *(const float4*)(src + 4);
      uint4 pk;
      pk.x = pack2(f0.x, f0.y); pk.y = pack2(f0.z, f0.w);
      pk.z = pack2(f1.x, f1.y); pk.w = pack2(f1.z, f1.w);
      *(uint4*)&As[(row<<8) + ((sl ^ (row&7))<<3)] = pk;   // swizzled dest
    } else {
      const u16* Ag = (const u16*)Ap + (size_t)mt*64*256;
      gload_lds16(Ag + row*256 + ((sl ^ (row&7))<<3), &As[ca<<3]);  // swizzled src
    }
  }
  #pragma unroll
  for (int i = 0; i < 4; ++i) {              // B: 1024 16B chunks
    int cb = tid + 256*i, row = cb >> 5, sl = cb & 31;
    const u16* Wg = W + (size_t)nt*32*256;
    gload_lds16(Wg + row*256 + ((sl ^ (row&7))<<3), &Bs[cb<<3]);
  }
  __syncthreads();
  const int w = tid >> 6, l = tid & 63, c = l & 15, q = l >> 4;
  f32x4 acc0 = {0.f,0.f,0.f,0.f}, acc1 = acc0;
  const int arow = w*16 + c;
  #pragma unroll
  for (int kb = 0; kb < 8; ++kb) {
    int ks = kb*4 + q;
    short8 af  = *(const short8*)&As[arow*256 + ((ks ^ (arow&7))<<3)];
    short8 bf0 = *(const short8*)&Bs[c*256        + ((ks ^ (c&7))<<3)];
    short8 bf1 = *(const short8*)&Bs[(16+c)*256   + ((ks ^ ((16+c)&7))<<3)];
    acc0 = __builtin_amdgcn_mfma_f32_16x16x32_bf16(af, bf0, acc0, 0,0,0);
    acc1 = __builtin_amdgcn_mfma_f32_16x16x32_bf16(af, bf1, acc1, 0,0,0);
  }
  #pragma unroll
  for (int nf = 0; nf < 2; ++nf) {
    int g = nt*32 + nf*16 + c;
    float bs = bias[g];
    f32x4 av = nf ? acc1 : acc0;
    #pragma unroll
    for (int r = 0; r < 4; ++r) {
      int m = mt*64 + w*16 + q*4 + r;
      out[(size_t)m*NG + g] = f2bf(av[r] + bs);
    }
  }
}

// ---------------------------------------------------------------------------
// GRU recurrence (R3 engine, verbatim except raw lgkm-only barrier).
// 16 wgs x 512 thr. Wave w owns j in [32w,32w+32), all 3 gates, Whh resident.
// Gate math deduped by jh-half (B-frag cols 8..15 duplicate cols 0..7).
// ---------------------------------------------------------------------------
__global__ __launch_bounds__(512, 1) void recur_kernel(
    const u16* __restrict__ xproj,   // [NB*NT][768] bf16, biases folded (r,z incl bhh)
    const float* __restrict__ Whh,   // [768][256] fp32
    const float* __restrict__ bhh,   // [768] fp32 (n part used)
    u16* __restrict__ outp,          // write_all: [NB][NT][256] ; else hT [NB][256]
    int write_all)
{
  const int b0 = blockIdx.x * 8;
  const int tid = threadIdx.x;
  const int w = tid >> 6, l = tid & 63, c = l & 15, q = l >> 4;
  const int jh = c >> 3;                 // this lane's extraction half
  const bool lo8 = (jh == 0);
  const int bb = b0 + (c & 7);           // this lane's batch
  const int jb = 32*w + jh*16 + q*4;     // this lane's 4-j base

  __shared__ __align__(16) u16 hfrag[2][8][512];   // 16 KB
  for (int i = tid; i < 4096; i += 512) ((u32*)hfrag)[i] = 0u;

  // ---- resident weight fragments wf[gate][jh][kb] (48 frags) ----
  short8 wf[3][2][8];
  #pragma unroll
  for (int g = 0; g < 3; ++g)
    #pragma unroll
    for (int jj = 0; jj < 2; ++jj) {
      const float* src = Whh + ((size_t)(g*NH + 32*w + jj*16 + c))*NI + q*8;
      #pragma unroll
      for (int kb = 0; kb < 8; ++kb) {
        float4 f0 = *(const float4*)(src + kb*32);
        float4 f1 = *(const float4*)(src + kb*32 + 4);
        short8 s;
        s[0]=(short)f2bf(f0.x); s[1]=(short)f2bf(f0.y);
        s[2]=(short)f2bf(f0.z); s[3]=(short)f2bf(f0.w);
        s[4]=(short)f2bf(f1.x); s[5]=(short)f2bf(f1.y);
        s[6]=(short)f2bf(f1.z); s[7]=(short)f2bf(f1.w);
        wf[g][jj][kb] = s;
      }
    }

  // n-gate hidden-bias as accumulator init vectors (j = 32w + q*4 + r  [+16])
  float4 bt0 = *(const float4*)&bhh[2*NH + 32*w + q*4];
  float4 bt1 = *(const float4*)&bhh[2*NH + 32*w + q*4 + 16];
  f32x4 bhn0; bhn0[0]=bt0.x; bhn0[1]=bt0.y; bhn0[2]=bt0.z; bhn0[3]=bt0.w;
  f32x4 bhn1; bhn1[0]=bt1.x; bhn1[1]=bt1.y; bhn1[2]=bt1.z; bhn1[3]=bt1.w;

  const u16* xptr = xproj + (size_t)bb*NT*NG + jb;
  uint2 xpr = *(const uint2*)(xptr);            // r-gate, 4 bf16
  uint2 xpz = *(const uint2*)(xptr + NH);
  uint2 xpn = *(const uint2*)(xptr + 2*NH);
  uint2 hpk; hpk.x = 0u; hpk.y = 0u;            // own 4 h_prev (bf16)

  const int lp = (c & 7) + 16*(2*jh + (q >> 1));
  __syncthreads();

  #pragma unroll 1
  for (int t = 0; t < NT; ++t) {
    const int cur = t & 1, nxt = cur ^ 1;

    // ---- hoisted B-fragment reads (8 x ds_read_b128, reused by all chains) --
    short8 bfr[8];
    #pragma unroll
    for (int kb = 0; kb < 8; ++kb) bfr[kb] = *(const short8*)&hfrag[cur][kb][l*8];

    // ---- prefetch next step's xproj ----
    const u16* xnx = xptr + (size_t)((t+1 < NT) ? t+1 : t)*NG;
    uint2 nxr = *(const uint2*)(xnx);
    uint2 nxz = *(const uint2*)(xnx + NH);
    uint2 nxn = *(const uint2*)(xnx + 2*NH);

    // ---- 6 independent 8-deep MFMA chains ----
    f32x4 z4 = {0.f,0.f,0.f,0.f};
    f32x4 ar0 = z4, az0 = z4, ar1 = z4, az1 = z4;
    f32x4 an0 = bhn0, an1 = bhn1;
    #pragma unroll
    for (int kb = 0; kb < 8; ++kb) {
      short8 bv = bfr[kb];
      ar0 = __builtin_amdgcn_mfma_f32_16x16x32_bf16(wf[0][0][kb], bv, ar0, 0,0,0);
      az0 = __builtin_amdgcn_mfma_f32_16x16x32_bf16(wf[1][0][kb], bv, az0, 0,0,0);
      an0 = __builtin_amdgcn_mfma_f32_16x16x32_bf16(wf[2][0][kb], bv, an0, 0,0,0);
      ar1 = __builtin_amdgcn_mfma_f32_16x16x32_bf16(wf[0][1][kb], bv, ar1, 0,0,0);
      az1 = __builtin_amdgcn_mfma_f32_16x16x32_bf16(wf[1][1][kb], bv, az1, 0,0,0);
      an1 = __builtin_amdgcn_mfma_f32_16x16x32_bf16(wf[2][1][kb], bv, an1, 0,0,0);
    }

    // ---- gate math: 4 h-values per lane (this lane's jh tile) ----
    float hv[4];
    #pragma unroll
    for (int r = 0; r < 4; ++r) {
      float arv = lo8 ? ar0[r] : ar1[r];
      float azv = lo8 ? az0[r] : az1[r];
      float anv = lo8 ? an0[r] : an1[r];     // includes bhh_n via init
      u32 xrw = (r < 2) ? xpr.x : xpr.y;
      u32 xzw = (r < 2) ? xpz.x : xpz.y;
      u32 xnw = (r < 2) ? xpn.x : xpn.y;
      u32 hpw = (r < 2) ? hpk.x : hpk.y;
      float xr = (r & 1) ? hi_bf(xrw) : lo_bf(xrw);
      float xz = (r & 1) ? hi_bf(xzw) : lo_bf(xzw);
      float xn = (r & 1) ? hi_bf(xnw) : lo_bf(xnw);
      float hp = (r & 1) ? hi_bf(hpw) : lo_bf(hpw);
      float rr = sigf(xr + arv);
      float zz = sigf(xz + azv);
      float nn = tanhf_(__builtin_fmaf(rr, anv, xn));
      hv[r] = __builtin_fmaf(zz, hp - nn, nn);   // (1-z)n + z h
    }
    hpk.x = pack_rne(hv[0], hv[1]);
    hpk.y = pack_rne(hv[2], hv[3]);

    // ---- write h into next B-frag (both column copies) + output ----
    u16* hdst = &hfrag[nxt][w][lp*8 + (q & 1)*4];
    *(uint2*)hdst        = hpk;   // cols 0..7
    *(uint2*)(hdst + 64) = hpk;   // duplicate cols 8..15
    if (write_all)
      *(uint2*)&outp[((size_t)bb*NT + t)*NH + jb] = hpk;
    else if (t == NT-1)
      *(uint2*)&outp[(size_t)bb*NH + jb] = hpk;

    xpr = nxr; xpz = nxz; xpn = nxn;

    // ---- raw barrier: LDS drain only (stores/prefetch stay in flight) ----
    asm volatile("s_waitcnt lgkmcnt(0)" ::: "memory");
    __builtin_amdgcn_s_barrier();
    __builtin_amdgcn_sched_barrier(0);
  }
}

// ---------------------------------------------------------------------------
__global__ __launch_bounds__(256) void fc_kernel(const u16* __restrict__ hT,
    const float* __restrict__ Wfc, const float* __restrict__ bfc, float* __restrict__ out)
{
  __shared__ float wv[NH];
  int tid = threadIdx.x;
  if (tid < NH) wv[tid] = Wfc[tid];
  __syncthreads();
  if (tid < NB) {
    float acc = bfc[0];
    for (int j = 0; j < NH; ++j) acc += lo_bf((u32)hT[tid*NH + j]) * wv[j];
    out[tid] = sigf(acc);
  }
}

// ---------------------------------------------------------------------------
extern "C" void kernel_launch(void* const* d_in, const int* in_sizes, int n_in,
                              void* d_out, int out_size, void* d_ws, size_t ws_size,
                              hipStream_t stream) {
  const float* x    = (const float*)d_in[0];
  const float* Wih0 = (const float*)d_in[1];
  const float* Whh0 = (const float*)d_in[2];
  const float* bih0 = (const float*)d_in[3];
  const float* bhh0 = (const float*)d_in[4];
  const float* Wih1 = (const float*)d_in[5];
  const float* Whh1 = (const float*)d_in[6];
  const float* bih1 = (const float*)d_in[7];
  const float* bhh1 = (const float*)d_in[8];
  const float* Wfc  = (const float*)d_in[9];
  const float* bfc  = (const float*)d_in[10];

  char* ws = (char*)d_ws;
  u16*   xproj = (u16*)ws;                                   // 100,663,296 B
  u16*   out0  = (u16*)(ws + 100663296);                     // 33,554,432 B (layer-0 out)
  u16*   w0bf  = (u16*)(ws + 134217728);                     // 384 KB
  u16*   w1bf  = (u16*)(ws + 134610944);                     // 384 KB
  float* bias0 = (float*)(ws + 135004160);                   // 3 KB
  float* bias1 = (float*)(ws + 135007232);                   // 3 KB
  u16*   hT    = (u16*)(ws + 135010304);                     // 64 KB

  convert_kernel<<<dim3(512), dim3(256), 0, stream>>>(
      Wih0, Wih1, bih0, bhh0, bih1, bhh1, w0bf, w1bf, bias0, bias1);
  gemm_proj<true ><<<dim3(1024*24), dim3(256), 0, stream>>>(x,    w0bf, bias0, xproj);
  recur_kernel<<<dim3(16), dim3(512), 0, stream>>>(xproj, Whh0, bhh0, out0, 1);
  gemm_proj<false><<<dim3(1024*24), dim3(256), 0, stream>>>(out0, w1bf, bias1, xproj);
  recur_kernel<<<dim3(16), dim3(512), 0, stream>>>(xproj, Whh1, bhh1, hT, 0);
  fc_kernel<<<dim3(1), dim3(256), 0, stream>>>(hT, Wfc, bfc, (float*)d_out);
}